// Round 6
// baseline (418.441 us; speedup 1.0000x reference)
//
#include <hip/hip_runtime.h>

// x: [16][256][32][32] f32, z: [16][64] f32, w_lin: [589824][64] f32
// out: [16][256][32][32] f32
// WgA layout (fragment-major): element (b, oc=ob*16+m, tap, ic=c*32+q*8+j) at
//   ((((b*16+ob)*9+tap)*8+c)*512 + (q*16+m)*8 + j   -> conv A-frag = 1KB contig
#define PB_ 589824
#define XT_PB 295936          // 34*34*256 padded per-batch elems
#define XGR 544               // granule slots per LDS buffer (4 padded rows * 34 pix * 4)
#define NBLK 1024             // persistent grid: 4 blocks/CU x 256 CUs, exact capacity
#define NPREP 5512            // prep units: 1152 K1 + 264 K2a + 4096 K2b
#define CTR_OFF 28344320      // ws offset of barrier counter (after WgA+xt)

typedef __bf16 bf16;
typedef __bf16 bf16x4 __attribute__((ext_vector_type(4)));
typedef __bf16 bf16x8 __attribute__((ext_vector_type(8)));
typedef float f32x4 __attribute__((ext_vector_type(4)));

static __device__ inline bf16x8 cvt8(float4 a, float4 b) {
  bf16x8 r;
  r[0] = (bf16)a.x; r[1] = (bf16)a.y; r[2] = (bf16)a.z; r[3] = (bf16)a.w;
  r[4] = (bf16)b.x; r[5] = (bf16)b.y; r[6] = (bf16)b.z; r[7] = (bf16)b.w;
  return r;
}

__global__ void zero_ctr(unsigned* c) { *c = 0u; }

// Fused persistent kernel: phase A = prep units (hyper GEMM / halo zero /
// x transpose, identical bodies to the 2-kernel version), device-wide
// release/acquire barrier (agent scope, cross-XCD safe), phase B = conv tile.
__global__ __launch_bounds__(256, 4) void fused_kernel(const float* __restrict__ z,
                                                       const float* __restrict__ wl,
                                                       const float* __restrict__ x,
                                                       bf16* __restrict__ WgA,
                                                       bf16* __restrict__ xt,
                                                       float* __restrict__ y,
                                                       unsigned* __restrict__ ctr) {
  __shared__ __align__(16) char smem[17408];   // union: K1 wsm 16K | K2b tile 2.1K | conv xs 17K
  const int g = blockIdx.x;
  const int tid = threadIdx.x;

  // ---------------- phase A: prep units u = g, g+1024, ... ----------------
  for (int u = g; u < NPREP; u += NBLK) {
    if (u < 1152) {
      // K1: hypernet GEMM. Block owns (ob, tap, c): 16 oc x 32 ic x 16 b.
      char* wsm = smem;
      const int c_  = u & 7;
      const int tap = (u >> 3) % 9;
      const int ob  = u / 72;
      const int lane = tid & 63;
      const int wave = tid >> 6;
      const int l15 = lane & 15;
      const int q = lane >> 4;

      const float* zp = z + l15 * 64 + q * 8;
      bf16x8 bz[2];
#pragma unroll
      for (int kc = 0; kc < 2; ++kc)
        bz[kc] = cvt8(*(const float4*)(zp + kc * 32), *(const float4*)(zp + kc * 32 + 4));

#pragma unroll
      for (int mi = 0; mi < 4; ++mi) {
        const int m = wave * 4 + mi;
#pragma unroll
        for (int h = 0; h < 2; ++h) {
          const long t = (long)(ob * 16 + m) * 2304 + (c_ * 32 + h * 16 + l15) * 9 + tap;
          const float* wp = wl + t * 64 + q * 8;
          f32x4 acc = {0.f, 0.f, 0.f, 0.f};
#pragma unroll
          for (int kc = 0; kc < 2; ++kc) {
            bf16x8 aw = cvt8(*(const float4*)(wp + kc * 32), *(const float4*)(wp + kc * 32 + 4));
            acc = __builtin_amdgcn_mfma_f32_16x16x32_bf16(aw, bz[kc], acc, 0, 0, 0);
          }
          bf16x4 o;
          o[0] = (bf16)acc[0]; o[1] = (bf16)acc[1]; o[2] = (bf16)acc[2]; o[3] = (bf16)acc[3];
          const int elem = ((h * 2 + (q >> 1)) * 16 + m) * 8 + (q & 1) * 4;
          int byte = (l15 << 10) + elem * 2;
          byte ^= (l15 & 7) << 4;
          *(bf16x4*)(wsm + byte) = o;
        }
      }
      __syncthreads();
      const int bb = tid >> 4;
      const int l16 = tid & 15;
      const long gbase = ((((long)bb * 16 + ob) * 9 + tap) * 8 + c_) * 512;
#pragma unroll
      for (int i = 0; i < 4; ++i) {
        int byte = (bb << 10) + (l16 << 4) + (i << 8);
        byte ^= (bb & 7) << 4;
        uint4 v = *(const uint4*)(wsm + byte);
        *(uint4*)(WgA + gbase + l16 * 8 + i * 128) = v;
      }
    } else if (u < 1416) {
      // K2a: zero halo border of padded xt.
      int gg = (u - 1152) * 256 + tid;
      int b = gg / 4224;
      int rem = gg - b * 4224;
      int pi = rem >> 5;
      int gq = rem & 31;
      int p;
      if (pi < 34) p = pi;
      else if (pi < 68) p = 1122 + (pi - 34);
      else {
        int kk = (pi - 68) >> 1;
        p = (kk + 1) * 34 + (((pi - 68) & 1) ? 33 : 0);
      }
      *(uint4*)(xt + (long)b * XT_PB + p * 256 + gq * 8) = make_uint4(0u, 0u, 0u, 0u);
    } else {
      // K2b: xt[b][(row+1)*34 + (col+1)][ic] = x[b][ic][row][col]
      bf16(*tile)[33] = (bf16(*)[33])smem;
      int i = u - 1416;
      int row = i & 31, c0 = ((i >> 5) & 7) * 32, b = i >> 8;
      int l = tid & 31;
      int r = tid >> 5;
#pragma unroll
      for (int j = 0; j < 4; ++j) {
        int ch = r + j * 8;
        tile[ch][l] = (bf16)x[((b * 256 + c0 + ch) * 1024) + row * 32 + l];
      }
      __syncthreads();
#pragma unroll
      for (int j = 0; j < 4; ++j) {
        int col = r + j * 8;
        xt[(long)b * XT_PB + ((row + 1) * 34 + (col + 1)) * 256 + c0 + l] = tile[l][col];
      }
    }
    __syncthreads();   // smem reuse hazard between units
  }

  // ---------------- device-wide barrier (release/acquire, agent scope) ----
  if (tid == 0) {
    __hip_atomic_fetch_add(ctr, 1u, __ATOMIC_RELEASE, __HIP_MEMORY_SCOPE_AGENT);
    while (__hip_atomic_load(ctr, __ATOMIC_ACQUIRE, __HIP_MEMORY_SCOPE_AGENT) < NBLK)
      __builtin_amdgcn_s_sleep(16);
  }
  __syncthreads();

  // ---------------- phase B: conv tile (id = blockIdx) --------------------
  {
    bf16* xsb = (bf16*)smem;               // [2][XGR*8]
    const int id = g;
    const int xcd = id & 7;
    const int k = id >> 3;
    const int b = ((k & 1) << 3) | xcd;
    const int r2 = k >> 1;
    const int mt = r2 & 3;
    const int nt = r2 >> 2;
    const int lane = tid & 63;
    const int wave = tid >> 6;
    const int wm = wave & 1;
    const int wn = wave >> 1;
    const int l15 = lane & 15;
    const int q = lane >> 4;
    const int oc0 = mt * 64;

    const bf16* xtb = xt + (long)b * XT_PB;
    const bf16* xstage = xtb + (nt * 2) * 34 * 256;
    const bf16* Wb = WgA + (long)b * PB_;

    f32x4 acc[2][2] = {};

#define STAGE(IC0, SEL)                                                          \
  for (int g0 = wave * 64; g0 < XGR; g0 += 256) {                                \
    int gg = g0 + lane;                                                          \
    int pix = gg >> 2, slot = gg & 3;                                            \
    int qq = slot ^ ((pix >> 1) & 3);                                            \
    if (gg < XGR) {                                                              \
      const bf16* src = xstage + (pix * 256 + (IC0) + qq * 8);                   \
      __builtin_amdgcn_global_load_lds(                                          \
          (const __attribute__((address_space(1))) void*)src,                    \
          (__attribute__((address_space(3))) void*)(xsb + (SEL) * (XGR * 8) +    \
                                                   g0 * 8), 16, 0, 0);           \
    }                                                                            \
  }

    STAGE(0, 0)
    for (int c = 0; c < 8; ++c) {
      __syncthreads();
      if (c < 7) { STAGE((c + 1) * 32, (c + 1) & 1) }
      const bf16* buf = xsb + (c & 1) * (XGR * 8);
#pragma unroll
      for (int tap = 0; tap < 9; ++tap) {
        const int kh = tap / 3, kw = tap % 3;
        bf16x8 afr[2];
#pragma unroll
        for (int mi = 0; mi < 2; ++mi) {
          const int ob = (oc0 >> 4) + wm * 2 + mi;
          afr[mi] = *(const bf16x8*)(Wb + (((ob * 9 + tap) * 8 + c) * 512 + lane * 8));
        }
        bf16x8 bfr[2];
#pragma unroll
        for (int n = 0; n < 2; ++n) {
          int pl = wn * 32 + n * 16;
          int pr = pl >> 5;
          int pc = (pl & 31) + l15;
          int spix = (pr + kh) * 34 + pc + kw;
          bfr[n] = *(const bf16x8*)(buf + spix * 32 + ((((spix >> 1) & 3) ^ q) * 8));
        }
#pragma unroll
        for (int mi = 0; mi < 2; ++mi)
#pragma unroll
          for (int n = 0; n < 2; ++n)
            acc[mi][n] = __builtin_amdgcn_mfma_f32_16x16x32_bf16(afr[mi], bfr[n],
                                                                 acc[mi][n], 0, 0, 0);
      }
    }

#pragma unroll
    for (int mi = 0; mi < 2; ++mi) {
      int ocb = oc0 + (wm * 2 + mi) * 16 + q * 4;
#pragma unroll
      for (int n = 0; n < 2; ++n) {
        int p = nt * 64 + wn * 32 + n * 16 + l15;
        float* yp = y + ((long)b * 256 + ocb) * 1024 + p;
#pragma unroll
        for (int rr = 0; rr < 4; ++rr)
          yp[rr * 1024] = acc[mi][n][rr];
      }
    }
#undef STAGE
  }
}

extern "C" void kernel_launch(void* const* d_in, const int* in_sizes, int n_in,
                              void* d_out, int out_size, void* d_ws, size_t ws_size,
                              hipStream_t stream) {
  const float* x  = (const float*)d_in[0];
  const float* z  = (const float*)d_in[1];
  const float* wl = (const float*)d_in[2];
  float* y = (float*)d_out;
  bf16* WgA = (bf16*)d_ws;                           // 18,874,368 B
  bf16* xt  = (bf16*)((char*)d_ws + 18874368);       // + 9,469,952 B
  unsigned* ctr = (unsigned*)((char*)d_ws + CTR_OFF);

  zero_ctr<<<1, 1, 0, stream>>>(ctr);
  fused_kernel<<<NBLK, 256, 0, stream>>>(z, wl, x, WgA, xt, y, ctr);
}

// Round 16
// 269.543 us; speedup vs baseline: 1.5524x; 1.5524x over previous
//
#include <hip/hip_runtime.h>

// x: [16][256][32][32] f32, z: [16][64] f32, w_lin: [589824][64] f32
// out: [16][256][32][32] f32
// WgA layout (fragment-major): element (b, oc=ob*16+m, tap, ic=c*32+q*8+j) at
//   ((((b*16+ob)*9+tap)*8+c)*512 + (q*16+m)*8 + j   -> conv A-frag = 1KB contig
#define PB_ 589824
#define XT_PB 295936          // 34*34*256 padded per-batch elems
#define XGR 544               // granule slots per LDS buffer (4 padded rows * 34 pix * 4)

typedef __bf16 bf16;
typedef __bf16 bf16x4 __attribute__((ext_vector_type(4)));
typedef __bf16 bf16x8 __attribute__((ext_vector_type(8)));
typedef float f32x4 __attribute__((ext_vector_type(4)));

static __device__ inline bf16x8 cvt8(float4 a, float4 b) {
  bf16x8 r;
  r[0] = (bf16)a.x; r[1] = (bf16)a.y; r[2] = (bf16)a.z; r[3] = (bf16)a.w;
  r[4] = (bf16)b.x; r[5] = (bf16)b.y; r[6] = (bf16)b.z; r[7] = (bf16)b.w;
  return r;
}

// --- fused prep: blocks [0,1152) hyper GEMM, [1152,1416) halo zero,
//     [1416,5512) x transpose. (identical to R5 champion) ---
__global__ __launch_bounds__(256) void prep_kernel(const float* __restrict__ z,
                                                   const float* __restrict__ wl,
                                                   const float* __restrict__ x,
                                                   bf16* __restrict__ WgA,
                                                   bf16* __restrict__ xt) {
  const int bid = blockIdx.x;
  if (bid < 1152) {
    __shared__ __align__(16) char wsm[16384];   // [b=16][512 elem] bf16, swizzled
    const int c_  = bid & 7;
    const int tap = (bid >> 3) % 9;
    const int ob  = bid / 72;
    const int lane = threadIdx.x & 63;
    const int wave = threadIdx.x >> 6;          // 0..3 -> m-quad
    const int l15 = lane & 15;
    const int q = lane >> 4;

    const float* zp = z + l15 * 64 + q * 8;
    bf16x8 bz[2];
#pragma unroll
    for (int kc = 0; kc < 2; ++kc)
      bz[kc] = cvt8(*(const float4*)(zp + kc * 32), *(const float4*)(zp + kc * 32 + 4));

#pragma unroll
    for (int mi = 0; mi < 4; ++mi) {
      const int m = wave * 4 + mi;              // oc low nibble
#pragma unroll
      for (int h = 0; h < 2; ++h) {             // 16-ic half of the 32-ic chunk
        const long t = (long)(ob * 16 + m) * 2304 + (c_ * 32 + h * 16 + l15) * 9 + tap;
        const float* wp = wl + t * 64 + q * 8;
        f32x4 acc = {0.f, 0.f, 0.f, 0.f};
#pragma unroll
        for (int kc = 0; kc < 2; ++kc) {
          bf16x8 aw = cvt8(*(const float4*)(wp + kc * 32), *(const float4*)(wp + kc * 32 + 4));
          acc = __builtin_amdgcn_mfma_f32_16x16x32_bf16(aw, bz[kc], acc, 0, 0, 0);
        }
        bf16x4 o;
        o[0] = (bf16)acc[0]; o[1] = (bf16)acc[1]; o[2] = (bf16)acc[2]; o[3] = (bf16)acc[3];
        const int elem = ((h * 2 + (q >> 1)) * 16 + m) * 8 + (q & 1) * 4;
        int byte = (l15 << 10) + elem * 2;
        byte ^= (l15 & 7) << 4;                 // bank swizzle, bijective per b-row
        *(bf16x4*)(wsm + byte) = o;
      }
    }
    __syncthreads();
    const int b = threadIdx.x >> 4;
    const int l16 = threadIdx.x & 15;
    const long gbase = ((((long)b * 16 + ob) * 9 + tap) * 8 + c_) * 512;
#pragma unroll
    for (int i = 0; i < 4; ++i) {
      int byte = (b << 10) + (l16 << 4) + (i << 8);
      byte ^= (b & 7) << 4;
      uint4 v = *(const uint4*)(wsm + byte);
      *(uint4*)(WgA + gbase + l16 * 8 + i * 128) = v;
    }
  } else if (bid < 1416) {
    // K2a: zero halo border of padded xt.
    int g = (bid - 1152) * 256 + threadIdx.x;      // 67584 granules
    int b = g / 4224;
    int rem = g - b * 4224;
    int pi = rem >> 5;
    int gq = rem & 31;
    int p;
    if (pi < 34) p = pi;
    else if (pi < 68) p = 1122 + (pi - 34);
    else {
      int k = (pi - 68) >> 1;
      p = (k + 1) * 34 + (((pi - 68) & 1) ? 33 : 0);
    }
    *(uint4*)(xt + (long)b * XT_PB + p * 256 + gq * 8) = make_uint4(0u, 0u, 0u, 0u);
  } else {
    // K2b: xt[b][(row+1)*34 + (col+1)][ic] = x[b][ic][row][col]
    __shared__ bf16 tile[32][33];
    int i = bid - 1416;                // 4096 blocks
    int row = i & 31, c0 = ((i >> 5) & 7) * 32, b = i >> 8;
    int l = threadIdx.x & 31;
    int r = threadIdx.x >> 5;
#pragma unroll
    for (int j = 0; j < 4; ++j) {
      int ch = r + j * 8;
      tile[ch][l] = (bf16)x[((b * 256 + c0 + ch) * 1024) + row * 32 + l];
    }
    __syncthreads();
#pragma unroll
    for (int j = 0; j < 4; ++j) {
      int col = r + j * 8;
      xt[(long)b * XT_PB + ((row + 1) * 34 + (col + 1)) * 256 + c0 + l] = tile[l][col];
    }
  }
}

// K3: implicit-GEMM conv. 256 threads = 4 waves as 2(wm) x 2(wn); grid 1024
// (4 blocks/CU). MLP fix (R6 diagnosis: all pipes idle at 47% occupancy,
// VGPR=64 -> load serialization): A-frags batch-loaded one kh-row ahead into
// a register ping-pong; global load sequence t = c*3+kh uses slot t&1, made
// compile-time by unrolling the c-loop in pairs. 6 independent 16B loads in
// flight under each row's LDS reads + MFMAs.
__global__ __launch_bounds__(256, 4) void conv_kernel(const bf16* __restrict__ WgA,
                                                      const bf16* __restrict__ xt,
                                                      float* __restrict__ y) {
  __shared__ __align__(16) bf16 xs[2][XGR * 8];
  const int id = blockIdx.x;
  const int xcd = id & 7;
  const int k = id >> 3;                // 0..127
  const int b = ((k & 1) << 3) | xcd;   // XCD xcd handles batches {xcd, xcd+8}
  const int r2 = k >> 1;                // 0..63
  const int mt = r2 & 3;                // oc tile (64)
  const int nt = r2 >> 2;               // 2-image-row pixel tile (64), 0..15
  const int tid = threadIdx.x;
  const int lane = tid & 63;
  const int wave = tid >> 6;            // 0..3
  const int wm = wave & 1;              // 0..1 (32-oc half)
  const int wn = wave >> 1;             // 0..1 (32-pixel half)
  const int l15 = lane & 15;
  const int q = lane >> 4;
  const int oc0 = mt * 64;

  const bf16* xtb = xt + (long)b * XT_PB;
  const bf16* xstage = xtb + (nt * 2) * 34 * 256;   // padded rows nt*2 .. nt*2+3
  const bf16* Wb = WgA + (long)b * PB_;             // frag-major, per-batch slice
  const bf16* Wlane = Wb + (long)((oc0 >> 4) + wm * 2) * 9 * 8 * 512 + lane * 8;
  // A-frag (mi, tap, c) at Wlane + ((mi*9 + tap)*8 + c)*512

  f32x4 acc[2][2] = {};
  bf16x8 afr[2][3][2];                  // [slot][kw][mi], all indices literal

#define LOADA(KH, C, SLOT)                                                       \
  {                                                                              \
    _Pragma("unroll")                                                            \
    for (int kw_ = 0; kw_ < 3; ++kw_)                                            \
      _Pragma("unroll")                                                          \
      for (int mi_ = 0; mi_ < 2; ++mi_)                                          \
        afr[SLOT][kw_][mi_] = *(const bf16x8*)(                                  \
            Wlane + (long)(((mi_ * 9 + (KH) * 3 + kw_) * 8 + (C)) * 512));       \
  }

#define STAGE(IC0, SEL)                                                          \
  for (int g0 = wave * 64; g0 < XGR; g0 += 256) {                                \
    int g = g0 + lane;                                                           \
    int pix = g >> 2, slot = g & 3;                                              \
    int qq = slot ^ ((pix >> 1) & 3);                                            \
    if (g < XGR) {                                                               \
      const bf16* src = xstage + (pix * 256 + (IC0) + qq * 8);                   \
      __builtin_amdgcn_global_load_lds(                                          \
          (const __attribute__((address_space(1))) void*)src,                    \
          (__attribute__((address_space(3))) void*)(&xs[SEL][g0 * 8]), 16, 0, 0);\
    }                                                                            \
  }

// One kh-row: MFMAs on afr[SLOT], prefetch macro PF first (next row's loads)
#define ROW(KH, SLOT, BUF, PF)                                                   \
  {                                                                              \
    PF                                                                           \
    _Pragma("unroll")                                                            \
    for (int kw = 0; kw < 3; ++kw) {                                             \
      bf16x8 bfr[2];                                                             \
      _Pragma("unroll")                                                          \
      for (int n = 0; n < 2; ++n) {                                              \
        int pl = wn * 32 + n * 16;                                               \
        int pr = pl >> 5;                                                        \
        int pc = (pl & 31) + l15;                                                \
        int spix = (pr + (KH)) * 34 + pc + kw;                                   \
        bfr[n] = *(const bf16x8*)((BUF) + spix * 32 +                            \
                                  ((((spix >> 1) & 3) ^ q) * 8));                \
      }                                                                          \
      _Pragma("unroll")                                                          \
      for (int mi = 0; mi < 2; ++mi)                                             \
        _Pragma("unroll")                                                        \
        for (int n = 0; n < 2; ++n)                                              \
          acc[mi][n] = __builtin_amdgcn_mfma_f32_16x16x32_bf16(                  \
              afr[SLOT][kw][mi], bfr[n], acc[mi][n], 0, 0, 0);                   \
    }                                                                            \
  }

  STAGE(0, 0)
  LOADA(0, 0, 0)                          // t=0 -> slot 0
  for (int c2 = 0; c2 < 4; ++c2) {
    const int ce = c2 * 2;                // even c: rows t = 3c.. parity 0,1,0
    {
      __syncthreads();
      STAGE((ce + 1) * 32, (ce + 1) & 1)
      const bf16* buf = &xs[ce & 1][0];
      ROW(0, 0, buf, LOADA(1, ce, 1))
      ROW(1, 1, buf, LOADA(2, ce, 0))
      ROW(2, 0, buf, LOADA(0, ce + 1, 1))
    }
    {
      const int co = ce + 1;              // odd c: rows parity 1,0,1
      __syncthreads();
      if (co < 7) { STAGE((co + 1) * 32, (co + 1) & 1) }
      const bf16* buf = &xs[co & 1][0];
      ROW(0, 1, buf, LOADA(1, co, 0))
      ROW(1, 0, buf, LOADA(2, co, 1))
      if (co < 7) { ROW(2, 1, buf, LOADA(0, co + 1, 0)) }
      else        { ROW(2, 1, buf, ) }
    }
  }

  // epilogue: D[row=q*4+rr][col=l15]; row -> oc, col -> pixel
#pragma unroll
  for (int mi = 0; mi < 2; ++mi) {
    int ocb = oc0 + (wm * 2 + mi) * 16 + q * 4;
#pragma unroll
    for (int n = 0; n < 2; ++n) {
      int p = nt * 64 + wn * 32 + n * 16 + l15;
      float* yp = y + ((long)b * 256 + ocb) * 1024 + p;
#pragma unroll
      for (int rr = 0; rr < 4; ++rr)
        yp[rr * 1024] = acc[mi][n][rr];
    }
  }
#undef STAGE
#undef LOADA
#undef ROW
}

extern "C" void kernel_launch(void* const* d_in, const int* in_sizes, int n_in,
                              void* d_out, int out_size, void* d_ws, size_t ws_size,
                              hipStream_t stream) {
  const float* x  = (const float*)d_in[0];
  const float* z  = (const float*)d_in[1];
  const float* wl = (const float*)d_in[2];
  float* y = (float*)d_out;
  bf16* WgA = (bf16*)d_ws;                           // 18,874,368 B
  bf16* xt  = (bf16*)((char*)d_ws + 18874368);       // + 9,469,952 B

  prep_kernel<<<5512, 256, 0, stream>>>(z, wl, x, WgA, xt);
  conv_kernel<<<1024, 256, 0, stream>>>(WgA, xt, y);
}

// Round 17
// 255.956 us; speedup vs baseline: 1.6348x; 1.0531x over previous
//
#include <hip/hip_runtime.h>

// x: [16][256][32][32] f32, z: [16][64] f32, w_lin: [589824][64] f32
// out: [16][256][32][32] f32
// WgA layout (fragment-major): element (b, oc=ob*16+m, tap, ic=c*32+q*8+j) at
//   ((((b*16+ob)*9+tap)*8+c)*512 + (q*16+m)*8 + j   -> conv A-frag = 1KB contig
#define PB_ 589824
#define XT_PB 295936          // 34*34*256 padded per-batch elems
#define XGR2 816              // conv v3: 6 padded rows * 34 pix * 4 granules

typedef __bf16 bf16;
typedef __bf16 bf16x4 __attribute__((ext_vector_type(4)));
typedef __bf16 bf16x8 __attribute__((ext_vector_type(8)));
typedef float f32x4 __attribute__((ext_vector_type(4)));

static __device__ inline bf16x8 cvt8(float4 a, float4 b) {
  bf16x8 r;
  r[0] = (bf16)a.x; r[1] = (bf16)a.y; r[2] = (bf16)a.z; r[3] = (bf16)a.w;
  r[4] = (bf16)b.x; r[5] = (bf16)b.y; r[6] = (bf16)b.z; r[7] = (bf16)b.w;
  return r;
}

// --- fused prep: blocks [0,1152) hyper GEMM, [1152,1416) halo zero,
//     [1416,5512) x transpose. (identical to R5 champion) ---
__global__ __launch_bounds__(256) void prep_kernel(const float* __restrict__ z,
                                                   const float* __restrict__ wl,
                                                   const float* __restrict__ x,
                                                   bf16* __restrict__ WgA,
                                                   bf16* __restrict__ xt) {
  const int bid = blockIdx.x;
  if (bid < 1152) {
    __shared__ __align__(16) char wsm[16384];   // [b=16][512 elem] bf16, swizzled
    const int c_  = bid & 7;
    const int tap = (bid >> 3) % 9;
    const int ob  = bid / 72;
    const int lane = threadIdx.x & 63;
    const int wave = threadIdx.x >> 6;          // 0..3 -> m-quad
    const int l15 = lane & 15;
    const int q = lane >> 4;

    const float* zp = z + l15 * 64 + q * 8;
    bf16x8 bz[2];
#pragma unroll
    for (int kc = 0; kc < 2; ++kc)
      bz[kc] = cvt8(*(const float4*)(zp + kc * 32), *(const float4*)(zp + kc * 32 + 4));

#pragma unroll
    for (int mi = 0; mi < 4; ++mi) {
      const int m = wave * 4 + mi;              // oc low nibble
#pragma unroll
      for (int h = 0; h < 2; ++h) {             // 16-ic half of the 32-ic chunk
        const long t = (long)(ob * 16 + m) * 2304 + (c_ * 32 + h * 16 + l15) * 9 + tap;
        const float* wp = wl + t * 64 + q * 8;
        f32x4 acc = {0.f, 0.f, 0.f, 0.f};
#pragma unroll
        for (int kc = 0; kc < 2; ++kc) {
          bf16x8 aw = cvt8(*(const float4*)(wp + kc * 32), *(const float4*)(wp + kc * 32 + 4));
          acc = __builtin_amdgcn_mfma_f32_16x16x32_bf16(aw, bz[kc], acc, 0, 0, 0);
        }
        bf16x4 o;
        o[0] = (bf16)acc[0]; o[1] = (bf16)acc[1]; o[2] = (bf16)acc[2]; o[3] = (bf16)acc[3];
        const int elem = ((h * 2 + (q >> 1)) * 16 + m) * 8 + (q & 1) * 4;
        int byte = (l15 << 10) + elem * 2;
        byte ^= (l15 & 7) << 4;                 // bank swizzle, bijective per b-row
        *(bf16x4*)(wsm + byte) = o;
      }
    }
    __syncthreads();
    const int b = threadIdx.x >> 4;
    const int l16 = threadIdx.x & 15;
    const long gbase = ((((long)b * 16 + ob) * 9 + tap) * 8 + c_) * 512;
#pragma unroll
    for (int i = 0; i < 4; ++i) {
      int byte = (b << 10) + (l16 << 4) + (i << 8);
      byte ^= (b & 7) << 4;
      uint4 v = *(const uint4*)(wsm + byte);
      *(uint4*)(WgA + gbase + l16 * 8 + i * 128) = v;
    }
  } else if (bid < 1416) {
    // K2a: zero halo border of padded xt.
    int g = (bid - 1152) * 256 + threadIdx.x;      // 67584 granules
    int b = g / 4224;
    int rem = g - b * 4224;
    int pi = rem >> 5;
    int gq = rem & 31;
    int p;
    if (pi < 34) p = pi;
    else if (pi < 68) p = 1122 + (pi - 34);
    else {
      int k = (pi - 68) >> 1;
      p = (k + 1) * 34 + (((pi - 68) & 1) ? 33 : 0);
    }
    *(uint4*)(xt + (long)b * XT_PB + p * 256 + gq * 8) = make_uint4(0u, 0u, 0u, 0u);
  } else {
    // K2b: xt[b][(row+1)*34 + (col+1)][ic] = x[b][ic][row][col]
    __shared__ bf16 tile[32][33];
    int i = bid - 1416;                // 4096 blocks
    int row = i & 31, c0 = ((i >> 5) & 7) * 32, b = i >> 8;
    int l = threadIdx.x & 31;
    int r = threadIdx.x >> 5;
#pragma unroll
    for (int j = 0; j < 4; ++j) {
      int ch = r + j * 8;
      tile[ch][l] = (bf16)x[((b * 256 + c0 + ch) * 1024) + row * 32 + l];
    }
    __syncthreads();
#pragma unroll
    for (int j = 0; j < 4; ++j) {
      int col = r + j * 8;
      xt[(long)b * XT_PB + ((row + 1) * 34 + (col + 1)) * 256 + c0 + l] = tile[l][col];
    }
  }
}

// K3 v3: implicit-GEMM conv, traffic-optimized (R16 diagnosis: conv ~80us vs
// ~6us instr floor; WgA re-read = 18.9MB x 32 (16 nt-tiles x 2 waves/ob) =
// 605MB, L3-serviced -> BW-bound. Both prior conv restructures kept the 32x
// multiplier -> neutral, confirming traffic as the binding term).
// New mapping: 512 blocks = 16b x 4mt x 8nt, 4 waves; EACH WAVE OWNS ONE ob
// (zero intra-block A-redundancy) x 128 pixels (8 n-frags). Multiplier:
// (1024/128) x 1 = 8x -> 151MB; nt doesn't change id&7, so all 8 sharers run
// on one XCD whose L2 (2.36MB WgA + 1.18MB xt for its 2 batches) captures the
// reuse. Staging geometry (816 granules, 6 padded rows) and XOR swizzle are
// the R0/R5-proven ones; A-frag kh-row ping-pong parity from R16 (3 frags/row).
__global__ __launch_bounds__(256, 2) void conv_kernel(const bf16* __restrict__ WgA,
                                                      const bf16* __restrict__ xt,
                                                      float* __restrict__ y) {
  __shared__ __align__(16) bf16 xs[2][XGR2 * 8];
  const int id = blockIdx.x;
  const int xcd = id & 7;
  const int k = id >> 3;                // 0..63
  const int b = ((k & 1) << 3) | xcd;   // XCD xcd handles batches {xcd, xcd+8}
  const int r2 = k >> 1;                // 0..31
  const int mt = r2 & 3;                // oc tile (64)
  const int nt = r2 >> 2;               // 4-image-row pixel tile (128), 0..7
  const int tid = threadIdx.x;
  const int lane = tid & 63;
  const int wave = tid >> 6;            // 0..3 = ob index within mt
  const int l15 = lane & 15;
  const int q = lane >> 4;

  const bf16* xtb = xt + (long)b * XT_PB;
  const bf16* xstage = xtb + (nt * 4) * 34 * 256;   // padded rows nt*4 .. nt*4+5
  const bf16* Wb = WgA + (long)b * PB_;             // frag-major, per-batch slice
  const int ob = mt * 4 + wave;
  const bf16* Wlane = Wb + (long)ob * 9 * 8 * 512 + lane * 8;
  // A-frag (tap, c) at Wlane + ((tap*8 + c)*512)

  f32x4 acc[8] = {};
  bf16x8 afr[2][3];                     // [slot][kw], all indices literal

#define LOADA(KH, C, SLOT)                                                       \
  {                                                                              \
    _Pragma("unroll")                                                            \
    for (int kw_ = 0; kw_ < 3; ++kw_)                                            \
      afr[SLOT][kw_] = *(const bf16x8*)(                                         \
          Wlane + (long)((((KH) * 3 + kw_) * 8 + (C)) * 512));                   \
  }

#define STAGE(IC0, SEL)                                                          \
  for (int g0 = wave * 64; g0 < XGR2; g0 += 256) {                               \
    int g = g0 + lane;                                                           \
    int pix = g >> 2, slot = g & 3;                                              \
    int qq = slot ^ ((pix >> 1) & 3);                                            \
    if (g < XGR2) {                                                              \
      const bf16* src = xstage + (pix * 256 + (IC0) + qq * 8);                   \
      __builtin_amdgcn_global_load_lds(                                          \
          (const __attribute__((address_space(1))) void*)src,                    \
          (__attribute__((address_space(3))) void*)(&xs[SEL][g0 * 8]), 16, 0, 0);\
    }                                                                            \
  }

// One kh-row: 3 kw x 8 n MFMAs on afr[SLOT]; prefetch PF (next row) first.
#define ROW(KH, SLOT, BUF, PF)                                                   \
  {                                                                              \
    PF                                                                           \
    _Pragma("unroll")                                                            \
    for (int kw = 0; kw < 3; ++kw) {                                             \
      _Pragma("unroll")                                                          \
      for (int n = 0; n < 8; ++n) {                                              \
        int pl = n * 16;                                                         \
        int pr = pl >> 5;                                                        \
        int pc = (pl & 31) + l15;                                                \
        int spix = (pr + (KH)) * 34 + pc + kw;        /* 0..203 */               \
        bf16x8 bfr = *(const bf16x8*)((BUF) + spix * 32 +                        \
                                      ((((spix >> 1) & 3) ^ q) * 8));            \
        acc[n] = __builtin_amdgcn_mfma_f32_16x16x32_bf16(                        \
            afr[SLOT][kw], bfr, acc[n], 0, 0, 0);                                \
      }                                                                          \
    }                                                                            \
  }

  STAGE(0, 0)
  LOADA(0, 0, 0)                          // t=0 -> slot 0
  for (int c2 = 0; c2 < 4; ++c2) {
    const int ce = c2 * 2;                // even c: row parities 0,1,0
    {
      __syncthreads();
      STAGE((ce + 1) * 32, (ce + 1) & 1)
      const bf16* buf = &xs[ce & 1][0];
      ROW(0, 0, buf, LOADA(1, ce, 1))
      ROW(1, 1, buf, LOADA(2, ce, 0))
      ROW(2, 0, buf, LOADA(0, ce + 1, 1))
    }
    {
      const int co = ce + 1;              // odd c: row parities 1,0,1
      __syncthreads();
      if (co < 7) { STAGE((co + 1) * 32, (co + 1) & 1) }
      const bf16* buf = &xs[co & 1][0];
      ROW(0, 1, buf, LOADA(1, co, 0))
      ROW(1, 0, buf, LOADA(2, co, 1))
      if (co < 7) { ROW(2, 1, buf, LOADA(0, co + 1, 0)) }
      else        { ROW(2, 1, buf, ) }
    }
  }

  // epilogue: D[row=q*4+rr][col=l15]; row -> oc (within ob), col -> pixel
  {
    const int ocb = mt * 64 + wave * 16 + q * 4;
#pragma unroll
    for (int n = 0; n < 8; ++n) {
      int p = nt * 128 + n * 16 + l15;
      float* yp = y + ((long)b * 256 + ocb) * 1024 + p;
#pragma unroll
      for (int rr = 0; rr < 4; ++rr)
        yp[rr * 1024] = acc[n][rr];
    }
  }
#undef STAGE
#undef LOADA
#undef ROW
}

extern "C" void kernel_launch(void* const* d_in, const int* in_sizes, int n_in,
                              void* d_out, int out_size, void* d_ws, size_t ws_size,
                              hipStream_t stream) {
  const float* x  = (const float*)d_in[0];
  const float* z  = (const float*)d_in[1];
  const float* wl = (const float*)d_in[2];
  float* y = (float*)d_out;
  bf16* WgA = (bf16*)d_ws;                           // 18,874,368 B
  bf16* xt  = (bf16*)((char*)d_ws + 18874368);       // + 9,469,952 B

  prep_kernel<<<5512, 256, 0, stream>>>(z, wl, x, WgA, xt);
  conv_kernel<<<512, 256, 0, stream>>>(WgA, xt, y);
}